// Round 2
// baseline (812.218 us; speedup 1.0000x reference)
//
#include <hip/hip_runtime.h>
#include <math.h>

#define F_IN 256
#define CH   16
#define NL   7
#define SCAN_T 512
#define SCAN_E 16          // 8192 elems per scan block (2^13)

// ---------------------------------------------------------------- degree
__global__ void k_degree(const int* __restrict__ dst, int E, int* __restrict__ deg) {
    int i = blockIdx.x * blockDim.x + threadIdx.x;
    if (i < E) atomicAdd(&deg[dst[i]], 1);
}

// ---------------------------------------------------------------- scan (3 kernels): deg -> exclusive offsets
__global__ __launch_bounds__(SCAN_T) void k_scan_blocks(const int* __restrict__ deg,
                                                        int* __restrict__ offarr,
                                                        int* __restrict__ bsum, int N) {
    __shared__ int lds[SCAN_T];
    int t = threadIdx.x;
    int base = blockIdx.x * SCAN_T * SCAN_E;
    int v[SCAN_E];
    int s = 0;
#pragma unroll
    for (int i = 0; i < SCAN_E; ++i) {
        int idx = base + t * SCAN_E + i;
        v[i] = (idx < N) ? deg[idx] : 0;
        s += v[i];
    }
    lds[t] = s;
    __syncthreads();
    for (int d = 1; d < SCAN_T; d <<= 1) {
        int add = (t >= d) ? lds[t - d] : 0;
        __syncthreads();
        lds[t] += add;
        __syncthreads();
    }
    if (t == SCAN_T - 1) bsum[blockIdx.x] = lds[SCAN_T - 1];
    int run = (t > 0) ? lds[t - 1] : 0;   // exclusive prefix of this thread's chunk
#pragma unroll
    for (int i = 0; i < SCAN_E; ++i) {
        int idx = base + t * SCAN_E + i;
        if (idx < N) offarr[idx] = run;
        run += v[i];
    }
}

__global__ void k_scan_mid(int* __restrict__ bsum, int nb) {
    if (threadIdx.x == 0) {
        int s = 0;
        for (int b = 0; b < nb; ++b) { int v = bsum[b]; bsum[b] = s; s += v; }
    }
}

__global__ void k_scan_fix(int* __restrict__ offarr, const int* __restrict__ bsum, int N) {
    int i = blockIdx.x * blockDim.x + threadIdx.x;
    if (i < N) offarr[i] += bsum[i >> 13];
}

// ---------------------------------------------------------------- CSR build (counting-sort placement)
// After this kernel, offarr[d] == end of d's segment; start = end - deg[d].
__global__ void k_build(const int* __restrict__ src, const int* __restrict__ dst,
                        int* __restrict__ offarr, int* __restrict__ csr, int E) {
    int e = blockIdx.x * blockDim.x + threadIdx.x;
    if (e >= E) return;
    int pos = atomicAdd(&offarr[dst[e]], 1);
    csr[pos] = src[e];
}

// ---------------------------------------------------------------- gemm1: g = (x @ W0) * dinv
__global__ __launch_bounds__(256) void k_gemm1(const float* __restrict__ x,
                                               const float* __restrict__ W0,
                                               const int* __restrict__ deg,
                                               float* __restrict__ g, int N) {
    int lane = threadIdx.x & 63;
    int q = lane >> 4;   // quarter of K
    int c = lane & 15;   // output channel
    float w[64];
#pragma unroll
    for (int t = 0; t < 64; ++t) w[t] = W0[(q * 64 + t) * CH + c];

    int wave  = (blockIdx.x * blockDim.x + threadIdx.x) >> 6;
    int nwave = (gridDim.x * blockDim.x) >> 6;
    for (int row = wave; row < N; row += nwave) {
        const float4* xp = (const float4*)(x + row * F_IN + q * 64);
        float acc = 0.f;
#pragma unroll
        for (int t = 0; t < 16; ++t) {
            float4 v = xp[t];
            acc += v.x * w[4*t] + v.y * w[4*t+1] + v.z * w[4*t+2] + v.w * w[4*t+3];
        }
        acc += __shfl_xor(acc, 16);
        acc += __shfl_xor(acc, 32);
        if (q == 0) {
            float dinv = rsqrtf((float)(deg[row] + 1));
            g[row * CH + c] = acc * dinv;
        }
    }
}

// ---------------------------------------------------------------- agg1: gather layer1 + relu + @W1 + scale
// one wave per node; lane = eo*16 + c  (4 edges in flight x 16 channels)
__global__ __launch_bounds__(256) void k_agg1(const int* __restrict__ offarr,
                                              const int* __restrict__ deg,
                                              const int* __restrict__ csr,
                                              const float* __restrict__ g,
                                              const float* __restrict__ W1,
                                              float* __restrict__ g2, int N) {
    int node = (blockIdx.x * blockDim.x + threadIdx.x) >> 6;
    if (node >= N) return;
    int lane = threadIdx.x & 63;
    int eo = lane >> 4, c = lane & 15;
    int j = lane & 7;
    float w1[CH];
#pragma unroll
    for (int c2 = 0; c2 < CH; ++c2) w1[c2] = (j < NL) ? W1[c2 * NL + j] : 0.f;

    int cnt = deg[node];
    int end = offarr[node];           // post-build cursor == segment end
    float acc = 0.f;
    for (int e = end - cnt + eo; e < end; e += 4) {
        int s = csr[e];
        acc += g[s * CH + c];
    }
    acc += __shfl_xor(acc, 16);
    acc += __shfl_xor(acc, 32);
    float dinv = rsqrtf((float)(cnt + 1));
    float h = fmaxf(dinv * (acc + g[node * CH + c]), 0.f);
    // h for channel c lives (replicated) in lanes with lane&15==c. Dot with W1 via shuffles.
    float h2 = 0.f;
#pragma unroll
    for (int c2 = 0; c2 < CH; ++c2) h2 += __shfl(h, c2) * w1[c2];
    if (lane < 8) g2[node * 8 + lane] = h2 * dinv;   // lane 7 writes 0 (w1 zeroed)
}

// ---------------------------------------------------------------- agg2: gather layer2 + exp + 1
// one wave per node; lane = eo*8 + j  (8 edges in flight x 8 channels)
__global__ __launch_bounds__(256) void k_agg2(const int* __restrict__ offarr,
                                              const int* __restrict__ deg,
                                              const int* __restrict__ csr,
                                              const float* __restrict__ g2,
                                              float* __restrict__ out, int N) {
    int node = (blockIdx.x * blockDim.x + threadIdx.x) >> 6;
    if (node >= N) return;
    int lane = threadIdx.x & 63;
    int eo = lane >> 3, j = lane & 7;

    int cnt = deg[node];
    int end = offarr[node];
    float acc = 0.f;
    for (int e = end - cnt + eo; e < end; e += 8) {
        int s = csr[e];
        acc += g2[s * 8 + j];
    }
    acc += __shfl_xor(acc, 8);
    acc += __shfl_xor(acc, 16);
    acc += __shfl_xor(acc, 32);
    float dinv = rsqrtf((float)(cnt + 1));
    float val = __expf(dinv * (acc + g2[node * 8 + j])) + 1.0f;
    if (eo == 0 && j < NL) out[node * NL + j] = val;
}

extern "C" void kernel_launch(void* const* d_in, const int* in_sizes, int n_in,
                              void* d_out, int out_size, void* d_ws, size_t ws_size,
                              hipStream_t stream) {
    const float* x  = (const float*)d_in[0];
    const float* W0 = (const float*)d_in[1];
    const float* W1 = (const float*)d_in[2];
    const int*   ei = (const int*)d_in[3];

    const int N = in_sizes[0] / F_IN;       // 100000
    const int E = in_sizes[3] / 2;          // 3200000
    const int* src = ei;
    const int* dst = ei + E;

    // ws layout: deg[N] | offarr[N] | bsum[64] | csr[E] | g[N*16] | g2[N*8]
    int*   deg    = (int*)d_ws;
    int*   offarr = deg + N;
    int*   bsum   = offarr + N;
    int*   csr    = bsum + 64;
    float* g      = (float*)(csr + E);
    float* g2     = g + (size_t)N * CH;
    float* out    = (float*)d_out;

    const int NB = (N + SCAN_T * SCAN_E - 1) / (SCAN_T * SCAN_E);   // 13

    hipMemsetAsync(deg, 0, (size_t)N * sizeof(int), stream);

    k_degree<<<(E + 255) / 256, 256, 0, stream>>>(dst, E, deg);
    k_scan_blocks<<<NB, SCAN_T, 0, stream>>>(deg, offarr, bsum, N);
    k_scan_mid<<<1, 64, 0, stream>>>(bsum, NB);
    k_scan_fix<<<(N + 255) / 256, 256, 0, stream>>>(offarr, bsum, N);
    k_build<<<(E + 255) / 256, 256, 0, stream>>>(src, dst, offarr, csr, E);

    k_gemm1<<<2048, 256, 0, stream>>>(x, W0, deg, g, N);
    k_agg1<<<(N + 3) / 4, 256, 0, stream>>>(offarr, deg, csr, g, W1, g2, N);
    k_agg2<<<(N + 3) / 4, 256, 0, stream>>>(offarr, deg, csr, g2, out, N);
}